// Round 2
// baseline (515.067 us; speedup 1.0000x reference)
//
#include <hip/hip_runtime.h>

// Problem constants (from reference): z (8,128,4096) f32, codebook (1024,128) f32.
namespace {
constexpr int kB = 8, kD = 128, kT = 4096, kNC = 1024;
constexpr int TT = 64;            // t-tile per block
constexpr int NJ = 128;           // codes per LDS chunk
constexpr int NCH = kNC / NJ;     // 8 chunks
constexpr long long OFF_CODES = (long long)kB * kD * kT;        // 4194304
constexpr long long OFF_LOSS  = OFF_CODES + (long long)kB * kT; // 4227072
constexpr long long OFF_DIST  = OFF_LOSS + 1;                   // 4227073
}

__global__ void vq_zero_kernel(double* lacc) {
  if (threadIdx.x == 0 && blockIdx.x == 0) *lacc = 0.0;
}

__global__ __launch_bounds__(256) void vq_main_kernel(
    const float* __restrict__ z, const float* __restrict__ cb,
    float* __restrict__ out, double* __restrict__ lacc)
{
  __shared__ float  zs[kD * TT];          // z tile, [d][t]         32 KB
  __shared__ float  cs[NJ * (kD + 1)];    // code chunk, [j][d]+pad 66 KB
  __shared__ float  scf[kNC];             // fl32(sum fl32(c^2))     4 KB
  __shared__ float  szf[TT];              // fl32(sum fl32(z^2))    .25KB
  __shared__ float  rv[TT * 16];          // argmin partial vals     4 KB
  __shared__ int    ri[TT * 16];          // argmin partial idx      4 KB
  __shared__ int    cd[TT];               // final codes per t
  __shared__ double lw[4];                // per-wave loss partials

  const int tid  = threadIdx.x;
  const int bidx = blockIdx.x;
  const int b  = bidx >> 6;               // 64 t-tiles per batch
  const int t0 = (bidx & 63) * TT;
  const float* zb = z + (size_t)b * kD * kT;

  // ---- stage z tile: zs[d*TT + t] (coalesced along t) ----
  for (int k = 0; k < (kD * TT) / 256; ++k) {
    int idx = k * 256 + tid;
    int t = idx & (TT - 1);
    int d = idx >> 6;
    zs[d * TT + t] = zb[(size_t)d * kT + t0 + t];
  }
  // ---- codebook norms: f64 sum of f32 squares, rounded to f32 ----
  // (numpy: np.sum(fl32(c*c)); any f32-accurate value differs from numpy's
  //  pairwise sum by ~1e-11 -- negligible vs the 7.6e-6 dist grid)
  for (int k = 0; k < kNC / 256; ++k) {
    int j = k * 256 + tid;
    const float* cj = cb + j * kD;
    double s = 0.0;
    for (int d = 0; d < kD; ++d) { float v = cj[d]; float q = v * v; s += (double)q; }
    scf[j] = (float)s;
  }
  __syncthreads();
  // ---- ||z_t||^2: f64 sum of f32 squares, rounded to f32.
  // Differs from numpy's pairwise f32 sum by an exact multiple of
  // ulp(s_z) -> shifts every dist in the row by the same grid step,
  // preserving argmin and f32-tie structure.
  if (tid < TT) {
    double s = 0.0;
    for (int d = 0; d < kD; ++d) { float v = zs[d * TT + tid]; float q = v * v; s += (double)q; }
    szf[tid] = (float)s;
  }
  __syncthreads();

  const int tj = tid & 15;   // j-group lane (16)
  const int ti = tid >> 4;   // t-group (16 groups of 4 t)

  float minv[4];
  int   mini[4];
#pragma unroll
  for (int ii = 0; ii < 4; ++ii) { minv[ii] = 3.4e38f; mini[ii] = 0; }

  const long long dist_base = OFF_DIST + (long long)(b * kT + t0) * kNC;

  for (int ch = 0; ch < NCH; ++ch) {
    __syncthreads();  // protect cs reuse from previous chunk readers
    // stage code chunk: cs[j*(kD+1)+d] (coalesced along d)
    for (int k = 0; k < (NJ * kD) / 256; ++k) {
      int idx = k * 256 + tid;
      int j = idx >> 7;
      int d = idx & (kD - 1);
      cs[j * (kD + 1) + d] = cb[((size_t)(ch * NJ + j)) * kD + d];
    }
    __syncthreads();

    // f64 accumulation of m = z . c for a 4(t) x 8(j) micro-tile
    double acc[4][8];
#pragma unroll
    for (int ii = 0; ii < 4; ++ii)
#pragma unroll
      for (int jj = 0; jj < 8; ++jj) acc[ii][jj] = 0.0;

    for (int d = 0; d < kD; ++d) {
      float4 zf = *reinterpret_cast<const float4*>(&zs[d * TT + ti * 4]);
      double z0 = (double)zf.x, z1 = (double)zf.y, z2 = (double)zf.z, z3 = (double)zf.w;
#pragma unroll
      for (int jj = 0; jj < 8; ++jj) {
        double cv = (double)cs[(16 * jj + tj) * (kD + 1) + d];
        acc[0][jj] += z0 * cv;
        acc[1][jj] += z1 * cv;
        acc[2][jj] += z2 * cv;
        acc[3][jj] += z3 * cv;
      }
    }

    // epilogue: numpy f32 rounding chain + running argmin (ascending j)
#pragma unroll
    for (int ii = 0; ii < 4; ++ii) {
      int t = ti * 4 + ii;
      float sz = szf[t];
      long long rowb = dist_base + (long long)t * kNC + ch * NJ;
#pragma unroll
      for (int jj = 0; jj < 8; ++jj) {
        int j = ch * NJ + 16 * jj + tj;
        float m32 = (float)acc[ii][jj];        // exactly-rounded dot product
        float d1  = sz - 2.0f * m32;           // f32 round (2*m32 exact)
        float dv  = d1 + scf[j];               // f32 round
        if (dv < minv[ii]) { minv[ii] = dv; mini[ii] = j; }
        out[rowb + 16 * jj + tj] = dv;
      }
    }
  }

  // ---- cross-thread argmin reduce (lexicographic: val, then lower index) ----
#pragma unroll
  for (int ii = 0; ii < 4; ++ii) {
    int t = ti * 4 + ii;
    rv[t * 16 + tj] = minv[ii];
    ri[t * 16 + tj] = mini[ii];
  }
  __syncthreads();
  if (tid < TT) {
    float bv = rv[tid * 16];
    int   bi = ri[tid * 16];
    for (int k = 1; k < 16; ++k) {
      float v  = rv[tid * 16 + k];
      int   i2 = ri[tid * 16 + k];
      if (v < bv || (v == bv && i2 < bi)) { bv = v; bi = i2; }
    }
    cd[tid] = bi;
    out[OFF_CODES + (long long)b * kT + t0 + tid] = (float)bi;
  }
  __syncthreads();

  // ---- z_q output (f32 straight-through chain) + loss partial ----
  double ls = 0.0;
  for (int k = 0; k < (kD * TT) / 256; ++k) {
    int idx = k * 256 + tid;
    int t = idx & (TT - 1);
    int d = idx >> 6;
    float q  = cb[cd[t] * kD + d];
    float zv = zs[d * TT + t];
    float qs = zv + (q - zv);              // matches ref: z + fl(q - z)
    out[(long long)b * kD * kT + (long long)d * kT + t0 + t] = qs;
    double dd = (double)q - (double)zv;
    ls += dd * dd;
  }
#pragma unroll
  for (int off = 32; off > 0; off >>= 1) ls += __shfl_down(ls, off);
  if ((tid & 63) == 0) lw[tid >> 6] = ls;
  __syncthreads();
  if (tid == 0) atomicAdd(lacc, lw[0] + lw[1] + lw[2] + lw[3]);
}

__global__ void vq_fin_kernel(const double* lacc, float* out) {
  if (threadIdx.x == 0 && blockIdx.x == 0) {
    // loss = codebk + 0.25*commit = 1.25 * mean((z_q - z_t)^2)
    out[OFF_LOSS] = (float)(*lacc * (1.25 / (double)((long long)kB * kT * kD)));
  }
}

extern "C" void kernel_launch(void* const* d_in, const int* in_sizes, int n_in,
                              void* d_out, int out_size, void* d_ws, size_t ws_size,
                              hipStream_t stream) {
  const float* z  = (const float*)d_in[0];
  const float* cb = (const float*)d_in[1];
  float* out = (float*)d_out;
  double* lacc = (double*)d_ws;

  vq_zero_kernel<<<1, 64, 0, stream>>>(lacc);
  vq_main_kernel<<<kB * (kT / TT), 256, 0, stream>>>(z, cb, out, lacc);
  vq_fin_kernel<<<1, 64, 0, stream>>>(lacc, out);
}

// Round 3
// 105.207 us; speedup vs baseline: 4.8958x; 4.8958x over previous
//
#include <hip/hip_runtime.h>

typedef __attribute__((ext_vector_type(8))) short short8;
typedef __attribute__((ext_vector_type(4))) float f32x4;

namespace {
constexpr long long OFF_CODES = 4194304;        // 8*128*4096
constexpr long long OFF_LOSS  = 4227072;        // + 8*4096
constexpr long long OFF_DIST  = 4227073;
constexpr float EPS = 1e-4f;                    // > 2*delta_max (~7.6e-5)
// ws byte offsets
constexpr size_t WS_LACC = 0;
constexpr size_t WS_SCF  = 1024;                // 1024 f32
constexpr size_t WS_SZF  = 8192;                // 32768 f32
constexpr size_t WS_FLAG = 139264;              // 32768 u32
constexpr size_t WS_CBHI = 270336;              // 1024*128 u16
constexpr size_t WS_CBLO = 532480;              // 1024*128 u16 (end 794624)
}

__device__ __forceinline__ unsigned short bf_rne(float v) {
  unsigned int u = __float_as_uint(v);
  unsigned int r = u + 0x7FFFu + ((u >> 16) & 1u);
  return (unsigned short)(r >> 16);
}
__device__ __forceinline__ float bf_to_f(unsigned short h) {
  return __uint_as_float(((unsigned int)h) << 16);
}

// ---- prep: codebook -> bf16 hi/lo splits + f32 norms (f64-accumulated) ----
__global__ __launch_bounds__(128) void vq_prep(
    const float* __restrict__ cb, unsigned short* __restrict__ cbhi,
    unsigned short* __restrict__ cblo, float* __restrict__ scf, double* lacc)
{
  __shared__ double p[128];
  int j = blockIdx.x, d = threadIdx.x;
  float v = cb[j * 128 + d];
  unsigned short h = bf_rne(v);
  float r = v - bf_to_f(h);                      // exact (Sterbenz)
  cbhi[j * 128 + d] = h;
  cblo[j * 128 + d] = bf_rne(r);
  float q = v * v;
  p[d] = (double)q;
  __syncthreads();
  for (int off = 64; off > 0; off >>= 1) {
    if (d < off) p[d] += p[d + off];
    __syncthreads();
  }
  if (d == 0) scf[j] = (float)p[0];
  if (j == 0 && d == 0) *lacc = 0.0;
}

// ---- main: dist (bf16-split MFMA) + prelim argmin + ambiguity flags ----
__global__ __launch_bounds__(256) void vq_main(
    const float* __restrict__ z,
    const unsigned short* __restrict__ cbhi,
    const unsigned short* __restrict__ cblo,
    const float* __restrict__ scf,
    float* __restrict__ szf, unsigned int* __restrict__ flags,
    float* __restrict__ out)
{
  __shared__ __align__(16) unsigned short zh[32 * 136];
  __shared__ __align__(16) unsigned short zl[32 * 136];
  __shared__ double part[32][8];
  __shared__ float szl[32];
  __shared__ float rm1[4][32];
  __shared__ float rm2[4][32];
  __shared__ int   ri1[4][32];

  const int tid = threadIdx.x;
  const int R0 = blockIdx.x * 32;                // 32 t-rows per block
  const int b  = R0 >> 12;
  const int t0 = R0 & 4095;
  const float* zb = z + (size_t)b * 524288;

  // stage z tile -> bf16 hi/lo, accumulate ||z||^2 partials (f64 of f32 squares)
  {
    double ps = 0.0;
    int t = tid & 31;
#pragma unroll
    for (int k = 0; k < 16; ++k) {
      int d = k * 8 + (tid >> 5);
      float v = zb[(size_t)d * 4096 + t0 + t];
      float q = v * v; ps += (double)q;
      unsigned short h = bf_rne(v);
      float r = v - bf_to_f(h);
      zh[t * 136 + d] = h;
      zl[t * 136 + d] = bf_rne(r);
    }
    part[t][tid >> 5] = ps;
  }
  __syncthreads();
  if (tid < 32) {
    double s = 0.0;
#pragma unroll
    for (int g = 0; g < 8; ++g) s += part[tid][g];
    float sz = (float)s;
    szl[tid] = sz;
    szf[R0 + tid] = sz;
  }
  __syncthreads();

  const int w = tid >> 6, l = tid & 63, lj = l & 15, lg = l >> 4;

  // A fragments (16x16x32: row=lane&15, k=(lane>>4)*8+i), kept in regs
  short8 Ah[2][4], Al[2][4];
#pragma unroll
  for (int tt = 0; tt < 2; ++tt)
#pragma unroll
    for (int ks = 0; ks < 4; ++ks) {
      int e = (tt * 16 + lj) * 136 + ks * 32 + lg * 8;
      Ah[tt][ks] = *reinterpret_cast<const short8*>(&zh[e]);
      Al[tt][ks] = *reinterpret_cast<const short8*>(&zl[e]);
    }
  float szr[2][4];
#pragma unroll
  for (int tt = 0; tt < 2; ++tt)
#pragma unroll
    for (int r = 0; r < 4; ++r) szr[tt][r] = szl[tt * 16 + lg * 4 + r];

  float m1[8], m2[8]; int i1[8];
#pragma unroll
  for (int s = 0; s < 8; ++s) { m1[s] = 3.4e38f; m2[s] = 3.4e38f; i1[s] = 0; }

  for (int jt = 0; jt < 16; ++jt) {
    const int j = w * 256 + jt * 16 + lj;        // wave owns a 256-code range
    const float sc = scf[j];
    f32x4 acc[2];
    acc[0] = (f32x4){0.f, 0.f, 0.f, 0.f};
    acc[1] = (f32x4){0.f, 0.f, 0.f, 0.f};
#pragma unroll
    for (int ks = 0; ks < 4; ++ks) {
      const size_t cbo = (size_t)j * 128 + ks * 32 + lg * 8;
      short8 bh = *reinterpret_cast<const short8*>(cbhi + cbo);
      short8 bl = *reinterpret_cast<const short8*>(cblo + cbo);
#pragma unroll
      for (int tt = 0; tt < 2; ++tt) {
        acc[tt] = __builtin_amdgcn_mfma_f32_16x16x32_bf16(Ah[tt][ks], bh, acc[tt], 0, 0, 0);
        acc[tt] = __builtin_amdgcn_mfma_f32_16x16x32_bf16(Al[tt][ks], bh, acc[tt], 0, 0, 0);
        acc[tt] = __builtin_amdgcn_mfma_f32_16x16x32_bf16(Ah[tt][ks], bl, acc[tt], 0, 0, 0);
      }
    }
    // epilogue: numpy chain fl(fl(sz - 2m) + sc), dist store, running min1/min2
#pragma unroll
    for (int tt = 0; tt < 2; ++tt)
#pragma unroll
      for (int r = 0; r < 4; ++r) {
        float m = acc[tt][r];
        float dv = (szr[tt][r] - 2.0f * m) + sc;
        int s = tt * 4 + r;
        bool lt1 = dv < m1[s];
        float old1 = m1[s];
        m2[s] = lt1 ? old1 : fminf(m2[s], dv);
        m1[s] = lt1 ? dv : old1;
        i1[s] = lt1 ? j : i1[s];
        int t = tt * 16 + lg * 4 + r;
        out[OFF_DIST + (size_t)(R0 + t) * 1024 + j] = dv;
      }
  }

  // in-wave 16-lane lexicographic (val,idx) reduce, tracking min2
#pragma unroll
  for (int s = 0; s < 8; ++s) {
    float a1 = m1[s]; int ai = i1[s]; float a2 = m2[s];
#pragma unroll
    for (int msk = 1; msk <= 8; msk <<= 1) {
      float b1 = __shfl_xor(a1, msk);
      int   bi = __shfl_xor(ai, msk);
      float b2 = __shfl_xor(a2, msk);
      bool keep = (a1 < b1) || (a1 == b1 && ai < bi);
      float lose = keep ? b1 : a1;
      a2 = fminf(fminf(a2, b2), lose);
      ai = keep ? ai : bi;
      a1 = keep ? a1 : b1;
    }
    if (lj == 0) {
      int t = (s >> 2) * 16 + lg * 4 + (s & 3);
      rm1[w][t] = a1; ri1[w][t] = ai; rm2[w][t] = a2;
    }
  }
  __syncthreads();
  if (tid < 32) {
    float f1 = rm1[0][tid]; int fi = ri1[0][tid]; float f2 = rm2[0][tid];
#pragma unroll
    for (int ww = 1; ww < 4; ++ww) {
      float b1 = rm1[ww][tid]; int bi = ri1[ww][tid]; float b2 = rm2[ww][tid];
      bool keep = (f1 < b1) || (f1 == b1 && fi < bi);
      float lose = keep ? b1 : f1;
      f2 = fminf(fminf(f2, b2), lose);
      fi = keep ? fi : bi;
      f1 = keep ? f1 : b1;
    }
    int R = R0 + tid;
    out[OFF_CODES + R] = (float)fi;
    flags[R] = (f2 - f1 <= EPS) ? 1u : 0u;
  }
}

// ---- refine: flagged rows get exact f64 dot + exact f32 chain, lex argmin ----
__global__ __launch_bounds__(256) void vq_refine(
    const float* __restrict__ z, const float* __restrict__ cb,
    const float* __restrict__ scf, const float* __restrict__ szf,
    const unsigned int* __restrict__ flags, float* __restrict__ out)
{
  const int w = threadIdx.x >> 6, l = threadIdx.x & 63;
  const int R = blockIdx.x * 4 + w;
  if (!flags[R]) return;
  const int b = R >> 12, t = R & 4095;

  const float* drow = out + OFF_DIST + (size_t)R * 1024;
  float v[16];
#pragma unroll
  for (int k = 0; k < 16; ++k) v[k] = drow[k * 64 + l];
  float mn = 3.4e38f;
#pragma unroll
  for (int k = 0; k < 16; ++k) mn = fminf(mn, v[k]);
#pragma unroll
  for (int msk = 1; msk <= 32; msk <<= 1) mn = fminf(mn, __shfl_xor(mn, msk));
  const float thresh = mn + EPS;

  const double zd0 = (double)z[(size_t)b * 524288 + (size_t)l * 4096 + t];
  const double zd1 = (double)z[(size_t)b * 524288 + (size_t)(l + 64) * 4096 + t];
  const float szv = szf[R];

  float bestv = 3.4e38f; int bestj = 1 << 30;
#pragma unroll
  for (int k = 0; k < 16; ++k) {
    unsigned long long msk = __ballot(v[k] <= thresh);
    while (msk) {
      int s = __ffsll((unsigned long long)msk) - 1;
      msk &= msk - 1;
      int jc = k * 64 + s;
      float c0 = cb[(size_t)jc * 128 + l];
      float c1 = cb[(size_t)jc * 128 + 64 + l];
      double m = zd0 * (double)c0 + zd1 * (double)c1;
#pragma unroll
      for (int mm = 1; mm <= 32; mm <<= 1) m += __shfl_xor(m, mm);
      float m32 = (float)m;
      float dvex = (szv - 2.0f * m32) + scf[jc];
      if (dvex < bestv || (dvex == bestv && jc < bestj)) { bestv = dvex; bestj = jc; }
    }
  }
  if (l == 0) out[OFF_CODES + R] = (float)bestj;
}

// ---- z_q + loss ----
__global__ __launch_bounds__(256) void vq_out_kernel(
    const float* __restrict__ z, const float* __restrict__ cb,
    float* __restrict__ out, double* __restrict__ lacc)
{
  __shared__ int ci[128];
  __shared__ float cq[128][129];
  __shared__ double lw[4];
  const int tid = threadIdx.x;
  const int b  = blockIdx.x >> 5;
  const int t0 = (blockIdx.x & 31) * 128;
  const int R0 = b * 4096 + t0;
  if (tid < 128) ci[tid] = (int)out[OFF_CODES + R0 + tid];
  __syncthreads();
  for (int r = 0; r < 128; r += 2) {
    int row = r + (tid >> 7);
    int d = tid & 127;
    cq[row][d] = cb[(size_t)ci[row] * 128 + d];
  }
  __syncthreads();
  double ls = 0.0;
  for (int dp = 0; dp < 128; dp += 2) {
    int d = dp + (tid >> 7);
    int t = tid & 127;
    size_t o = (size_t)b * 524288 + (size_t)d * 4096 + t0 + t;
    float zv = z[o];
    float q = cq[t][d];
    out[o] = zv + (q - zv);                      // straight-through f32 chain
    double dd = (double)q - (double)zv;
    ls += dd * dd;
  }
#pragma unroll
  for (int msk = 1; msk <= 32; msk <<= 1) ls += __shfl_xor(ls, msk);
  if ((tid & 63) == 0) lw[tid >> 6] = ls;
  __syncthreads();
  if (tid == 0) atomicAdd(lacc, lw[0] + lw[1] + lw[2] + lw[3]);
}

__global__ void vq_fin(const double* lacc, float* out) {
  if (threadIdx.x == 0 && blockIdx.x == 0)
    out[OFF_LOSS] = (float)(*lacc * (1.25 / 4194304.0));
}

extern "C" void kernel_launch(void* const* d_in, const int* in_sizes, int n_in,
                              void* d_out, int out_size, void* d_ws, size_t ws_size,
                              hipStream_t stream) {
  const float* z  = (const float*)d_in[0];
  const float* cb = (const float*)d_in[1];
  float* out = (float*)d_out;
  char* ws = (char*)d_ws;
  double* lacc = (double*)(ws + WS_LACC);
  float* scf = (float*)(ws + WS_SCF);
  float* szf = (float*)(ws + WS_SZF);
  unsigned int* flags = (unsigned int*)(ws + WS_FLAG);
  unsigned short* cbhi = (unsigned short*)(ws + WS_CBHI);
  unsigned short* cblo = (unsigned short*)(ws + WS_CBLO);

  vq_prep<<<1024, 128, 0, stream>>>(cb, cbhi, cblo, scf, lacc);
  vq_main<<<1024, 256, 0, stream>>>(z, cbhi, cblo, scf, szf, flags, out);
  vq_refine<<<8192, 256, 0, stream>>>(z, cb, scf, szf, flags, out);
  vq_out_kernel<<<256, 256, 0, stream>>>(z, cb, out, lacc);
  vq_fin<<<1, 64, 0, stream>>>(lacc, out);
}

// Round 4
// 101.444 us; speedup vs baseline: 5.0774x; 1.0371x over previous
//
#include <hip/hip_runtime.h>

typedef __attribute__((ext_vector_type(8))) short short8;
typedef __attribute__((ext_vector_type(4))) float f32x4;

namespace {
constexpr long long OFF_CODES = 4194304;        // 8*128*4096
constexpr long long OFF_LOSS  = 4227072;        // + 8*4096
constexpr long long OFF_DIST  = 4227073;
constexpr float EPS = 1e-4f;                    // > 2*delta_max (~7.6e-5)
// ws byte offsets
constexpr size_t WS_LACC = 0;
constexpr size_t WS_SCF  = 1024;                // 1024 f32
constexpr size_t WS_SZF  = 8192;                // 32768 f32
constexpr size_t WS_FLAG = 139264;              // 32768 u32
constexpr size_t WS_CBHI = 270336;              // 1024*128 u16
constexpr size_t WS_CBLO = 532480;              // 1024*128 u16 (end 794624)
}

__device__ __forceinline__ unsigned short bf_rne(float v) {
  unsigned int u = __float_as_uint(v);
  unsigned int r = u + 0x7FFFu + ((u >> 16) & 1u);
  return (unsigned short)(r >> 16);
}
__device__ __forceinline__ float bf_to_f(unsigned short h) {
  return __uint_as_float(((unsigned int)h) << 16);
}

// ---- prep: codebook -> bf16 hi/lo splits + f32 norms (f64-accumulated) ----
__global__ __launch_bounds__(128) void vq_prep(
    const float* __restrict__ cb, unsigned short* __restrict__ cbhi,
    unsigned short* __restrict__ cblo, float* __restrict__ scf, double* lacc)
{
  __shared__ double p[128];
  int j = blockIdx.x, d = threadIdx.x;
  float v = cb[j * 128 + d];
  unsigned short h = bf_rne(v);
  float r = v - bf_to_f(h);                      // exact (Sterbenz)
  cbhi[j * 128 + d] = h;
  cblo[j * 128 + d] = bf_rne(r);
  float q = v * v;
  p[d] = (double)q;
  __syncthreads();
  for (int off = 64; off > 0; off >>= 1) {
    if (d < off) p[d] += p[d + off];
    __syncthreads();
  }
  if (d == 0) scf[j] = (float)p[0];
  if (j == 0 && d == 0) *lacc = 0.0;
}

// ---- main: dist (bf16-split MFMA) + prelim argmin + ambiguity flags ----
// Block: 256 thr / 4 waves, 32 t-rows, all 1024 j in 16 windows of 64.
// Wave w owns cols w*16..w*16+15 of each window. Epilogue stages [32][64]
// in LDS, then 64-lane 256B row-contiguous stores (full sector coverage).
__global__ __launch_bounds__(256, 4) void vq_main(
    const float* __restrict__ z,
    const unsigned short* __restrict__ cbhi,
    const unsigned short* __restrict__ cblo,
    const float* __restrict__ scf,
    float* __restrict__ szf, unsigned int* __restrict__ flags,
    float* __restrict__ out)
{
  __shared__ __align__(16) unsigned short zh_sd[32 * 136]; // zh; later sd f32[32*68]
  __shared__ __align__(16) unsigned short zl[32 * 136];
  __shared__ double part[32][8];
  __shared__ float szl[32];
  __shared__ float scfl[1024];
  __shared__ float rm1[4][32];
  __shared__ float rm2[4][32];
  __shared__ int   ri1[4][32];

  const int tid = threadIdx.x;
  const int R0 = blockIdx.x * 32;                // 32 t-rows per block
  const int b  = R0 >> 12;
  const int t0 = R0 & 4095;
  const float* zb = z + (size_t)b * 524288;

  // stage scf -> LDS
#pragma unroll
  for (int k = 0; k < 4; ++k) scfl[k * 256 + tid] = scf[k * 256 + tid];

  // stage z tile -> bf16 hi/lo, accumulate ||z||^2 partials (f64 of f32 squares)
  {
    double ps = 0.0;
    int t = tid & 31;
#pragma unroll
    for (int k = 0; k < 16; ++k) {
      int d = k * 8 + (tid >> 5);
      float v = zb[(size_t)d * 4096 + t0 + t];
      float q = v * v; ps += (double)q;
      unsigned short h = bf_rne(v);
      float r = v - bf_to_f(h);
      zh_sd[t * 136 + d] = h;
      zl[t * 136 + d] = bf_rne(r);
    }
    part[t][tid >> 5] = ps;
  }
  __syncthreads();
  if (tid < 32) {
    double s = 0.0;
#pragma unroll
    for (int g = 0; g < 8; ++g) s += part[tid][g];
    float sz = (float)s;
    szl[tid] = sz;
    szf[R0 + tid] = sz;
  }
  __syncthreads();

  const int w = tid >> 6, l = tid & 63, lj = l & 15, lg = l >> 4;
  const int jcol = w * 16 + lj;                  // col within 64-wide window

  // A-hi fragments (16x16x32: row=lane&15, k=(lane>>4)*8+i) kept in regs;
  // A-lo stays in LDS (read per use) to hold VGPR <= 128.
  short8 Ah[2][4];
#pragma unroll
  for (int tt = 0; tt < 2; ++tt)
#pragma unroll
    for (int ks = 0; ks < 4; ++ks)
      Ah[tt][ks] = *reinterpret_cast<const short8*>(
          &zh_sd[(tt * 16 + lj) * 136 + ks * 32 + lg * 8]);
  float szr[2][4];
#pragma unroll
  for (int tt = 0; tt < 2; ++tt)
#pragma unroll
    for (int r = 0; r < 4; ++r) szr[tt][r] = szl[tt * 16 + lg * 4 + r];
  __syncthreads();                               // zh dead -> sd usable

  float* sd = reinterpret_cast<float*>(zh_sd);   // [32][68] f32 staging

  const unsigned short* pbh = cbhi + (size_t)jcol * 128 + lg * 8;
  const unsigned short* pbl = cblo + (size_t)jcol * 128 + lg * 8;

  float m1[8], m2[8]; int i1[8];
#pragma unroll
  for (int s = 0; s < 8; ++s) { m1[s] = 3.4e38f; m2[s] = 3.4e38f; i1[s] = 0; }

  // store-phase per-thread constants: row = (tid>>6) + step*4, col = tid&63
  float* outp = out + OFF_DIST + (size_t)(R0 + (tid >> 6)) * 1024 + (tid & 63);
  const int sread = (tid >> 6) * 68 + (tid & 63);

  for (int jt = 0; jt < 16; ++jt) {
    const int joff = jt * 64;
    const size_t cbj = (size_t)joff * 128;
    f32x4 acc0 = (f32x4){0.f, 0.f, 0.f, 0.f};
    f32x4 acc1 = (f32x4){0.f, 0.f, 0.f, 0.f};
#pragma unroll
    for (int ks = 0; ks < 4; ++ks) {
      short8 bh = *reinterpret_cast<const short8*>(pbh + cbj + ks * 32);
      short8 bl = *reinterpret_cast<const short8*>(pbl + cbj + ks * 32);
      short8 al0 = *reinterpret_cast<const short8*>(&zl[lj * 136 + ks * 32 + lg * 8]);
      short8 al1 = *reinterpret_cast<const short8*>(&zl[(16 + lj) * 136 + ks * 32 + lg * 8]);
      acc0 = __builtin_amdgcn_mfma_f32_16x16x32_bf16(Ah[0][ks], bh, acc0, 0, 0, 0);
      acc1 = __builtin_amdgcn_mfma_f32_16x16x32_bf16(Ah[1][ks], bh, acc1, 0, 0, 0);
      acc0 = __builtin_amdgcn_mfma_f32_16x16x32_bf16(al0, bh, acc0, 0, 0, 0);
      acc1 = __builtin_amdgcn_mfma_f32_16x16x32_bf16(al1, bh, acc1, 0, 0, 0);
      acc0 = __builtin_amdgcn_mfma_f32_16x16x32_bf16(Ah[0][ks], bl, acc0, 0, 0, 0);
      acc1 = __builtin_amdgcn_mfma_f32_16x16x32_bf16(Ah[1][ks], bl, acc1, 0, 0, 0);
    }
    // epilogue: numpy chain fl(fl(sz - 2m) + sc), min1/min2 update, LDS stage
    const float sc = scfl[joff + jcol];
    const int j = joff + jcol;
#pragma unroll
    for (int tt = 0; tt < 2; ++tt)
#pragma unroll
      for (int r = 0; r < 4; ++r) {
        float m = (tt == 0) ? acc0[r] : acc1[r];
        float dv = (szr[tt][r] - 2.0f * m) + sc;
        int s = tt * 4 + r;
        bool lt1 = dv < m1[s];
        float old1 = m1[s];
        m2[s] = lt1 ? old1 : fminf(m2[s], dv);
        m1[s] = lt1 ? dv : old1;
        i1[s] = lt1 ? j : i1[s];
        sd[(tt * 16 + lg * 4 + r) * 68 + jcol] = dv;
      }
    __syncthreads();
    // cooperative store: 8 steps x (4 rows x 64 cols); 256B contiguous per wave
#pragma unroll
    for (int step = 0; step < 8; ++step)
      outp[(size_t)step * 4096 + joff] = sd[sread + step * 272];
    __syncthreads();
  }

  // ---- in-wave 16-lane lexicographic (val,idx) reduce, tracking min2 ----
#pragma unroll
  for (int s = 0; s < 8; ++s) {
    float a1 = m1[s]; int ai = i1[s]; float a2 = m2[s];
#pragma unroll
    for (int msk = 1; msk <= 8; msk <<= 1) {
      float b1 = __shfl_xor(a1, msk);
      int   bi = __shfl_xor(ai, msk);
      float b2 = __shfl_xor(a2, msk);
      bool keep = (a1 < b1) || (a1 == b1 && ai < bi);
      float lose = keep ? b1 : a1;
      a2 = fminf(fminf(a2, b2), lose);
      ai = keep ? ai : bi;
      a1 = keep ? a1 : b1;
    }
    if (lj == 0) {
      int t = (s >> 2) * 16 + lg * 4 + (s & 3);
      rm1[w][t] = a1; ri1[w][t] = ai; rm2[w][t] = a2;
    }
  }
  __syncthreads();
  if (tid < 32) {
    float f1 = rm1[0][tid]; int fi = ri1[0][tid]; float f2 = rm2[0][tid];
#pragma unroll
    for (int ww = 1; ww < 4; ++ww) {
      float b1 = rm1[ww][tid]; int bi = ri1[ww][tid]; float b2 = rm2[ww][tid];
      bool keep = (f1 < b1) || (f1 == b1 && fi < bi);
      float lose = keep ? b1 : f1;
      f2 = fminf(fminf(f2, b2), lose);
      fi = keep ? fi : bi;
      f1 = keep ? f1 : b1;
    }
    int R = R0 + tid;
    out[OFF_CODES + R] = (float)fi;
    flags[R] = (f2 - f1 <= EPS) ? 1u : 0u;
  }
}

// ---- refine: flagged rows get exact f64 dot + exact f32 chain, lex argmin ----
__global__ __launch_bounds__(256) void vq_refine(
    const float* __restrict__ z, const float* __restrict__ cb,
    const float* __restrict__ scf, const float* __restrict__ szf,
    const unsigned int* __restrict__ flags, float* __restrict__ out)
{
  const int w = threadIdx.x >> 6, l = threadIdx.x & 63;
  const int R = blockIdx.x * 4 + w;
  if (!flags[R]) return;
  const int b = R >> 12, t = R & 4095;

  const float* drow = out + OFF_DIST + (size_t)R * 1024;
  float v[16];
#pragma unroll
  for (int k = 0; k < 16; ++k) v[k] = drow[k * 64 + l];
  float mn = 3.4e38f;
#pragma unroll
  for (int k = 0; k < 16; ++k) mn = fminf(mn, v[k]);
#pragma unroll
  for (int msk = 1; msk <= 32; msk <<= 1) mn = fminf(mn, __shfl_xor(mn, msk));
  const float thresh = mn + EPS;

  const double zd0 = (double)z[(size_t)b * 524288 + (size_t)l * 4096 + t];
  const double zd1 = (double)z[(size_t)b * 524288 + (size_t)(l + 64) * 4096 + t];
  const float szv = szf[R];

  float bestv = 3.4e38f; int bestj = 1 << 30;
#pragma unroll
  for (int k = 0; k < 16; ++k) {
    unsigned long long msk = __ballot(v[k] <= thresh);
    while (msk) {
      int s = __ffsll((unsigned long long)msk) - 1;
      msk &= msk - 1;
      int jc = k * 64 + s;
      float c0 = cb[(size_t)jc * 128 + l];
      float c1 = cb[(size_t)jc * 128 + 64 + l];
      double m = zd0 * (double)c0 + zd1 * (double)c1;
#pragma unroll
      for (int mm = 1; mm <= 32; mm <<= 1) m += __shfl_xor(m, mm);
      float m32 = (float)m;
      float dvex = (szv - 2.0f * m32) + scf[jc];
      if (dvex < bestv || (dvex == bestv && jc < bestj)) { bestv = dvex; bestj = jc; }
    }
  }
  if (l == 0) out[OFF_CODES + R] = (float)bestj;
}

// ---- z_q + loss ----
__global__ __launch_bounds__(256) void vq_out_kernel(
    const float* __restrict__ z, const float* __restrict__ cb,
    float* __restrict__ out, double* __restrict__ lacc)
{
  __shared__ int ci[128];
  __shared__ float cq[128][129];
  __shared__ double lw[4];
  const int tid = threadIdx.x;
  const int b  = blockIdx.x >> 5;
  const int t0 = (blockIdx.x & 31) * 128;
  const int R0 = b * 4096 + t0;
  if (tid < 128) ci[tid] = (int)out[OFF_CODES + R0 + tid];
  __syncthreads();
  for (int r = 0; r < 128; r += 2) {
    int row = r + (tid >> 7);
    int d = tid & 127;
    cq[row][d] = cb[(size_t)ci[row] * 128 + d];
  }
  __syncthreads();
  double ls = 0.0;
  for (int dp = 0; dp < 128; dp += 2) {
    int d = dp + (tid >> 7);
    int t = tid & 127;
    size_t o = (size_t)b * 524288 + (size_t)d * 4096 + t0 + t;
    float zv = z[o];
    float q = cq[t][d];
    out[o] = zv + (q - zv);                      // straight-through f32 chain
    double dd = (double)q - (double)zv;
    ls += dd * dd;
  }
#pragma unroll
  for (int msk = 1; msk <= 32; msk <<= 1) ls += __shfl_xor(ls, msk);
  if ((tid & 63) == 0) lw[tid >> 6] = ls;
  __syncthreads();
  if (tid == 0) atomicAdd(lacc, lw[0] + lw[1] + lw[2] + lw[3]);
}

__global__ void vq_fin(const double* lacc, float* out) {
  if (threadIdx.x == 0 && blockIdx.x == 0)
    out[OFF_LOSS] = (float)(*lacc * (1.25 / 4194304.0));
}

extern "C" void kernel_launch(void* const* d_in, const int* in_sizes, int n_in,
                              void* d_out, int out_size, void* d_ws, size_t ws_size,
                              hipStream_t stream) {
  const float* z  = (const float*)d_in[0];
  const float* cb = (const float*)d_in[1];
  float* out = (float*)d_out;
  char* ws = (char*)d_ws;
  double* lacc = (double*)(ws + WS_LACC);
  float* scf = (float*)(ws + WS_SCF);
  float* szf = (float*)(ws + WS_SZF);
  unsigned int* flags = (unsigned int*)(ws + WS_FLAG);
  unsigned short* cbhi = (unsigned short*)(ws + WS_CBHI);
  unsigned short* cblo = (unsigned short*)(ws + WS_CBLO);

  vq_prep<<<1024, 128, 0, stream>>>(cb, cbhi, cblo, scf, lacc);
  vq_main<<<1024, 256, 0, stream>>>(z, cbhi, cblo, scf, szf, flags, out);
  vq_refine<<<8192, 256, 0, stream>>>(z, cb, scf, szf, flags, out);
  vq_out_kernel<<<256, 256, 0, stream>>>(z, cb, out, lacc);
  vq_fin<<<1, 64, 0, stream>>>(lacc, out);
}

// Round 5
// 94.219 us; speedup vs baseline: 5.4667x; 1.0767x over previous
//
#include <hip/hip_runtime.h>

typedef __attribute__((ext_vector_type(8))) short short8;
typedef __attribute__((ext_vector_type(4))) float f32x4;

namespace {
constexpr long long OFF_CODES = 4194304;        // 8*128*4096
constexpr long long OFF_LOSS  = 4227072;        // + 8*4096
constexpr long long OFF_DIST  = 4227073;
constexpr float EPS = 5e-4f;                    // > 2*max dist err of bf16 product (~1.7e-4)
// ws byte offsets
constexpr size_t WS_LACC = 0;
constexpr size_t WS_SCF  = 1024;                // 1024 f32
constexpr size_t WS_SZF  = 8192;                // 32768 f32 (ends 139264)
constexpr size_t WS_FLAG = 139264;              // 32768 u32 (ends 270336)
constexpr size_t WS_CBH  = 270336;              // 1024*128 u16 (ends 532480)
}

__device__ __forceinline__ unsigned short bf_rne(float v) {
  unsigned int u = __float_as_uint(v);
  unsigned int r = u + 0x7FFFu + ((u >> 16) & 1u);
  return (unsigned short)(r >> 16);
}

// ---- prep: codebook -> bf16 + f32 norms (f64-accumulated); zero lacc ----
__global__ __launch_bounds__(256) void vq_prep(
    const float* __restrict__ cb, unsigned short* __restrict__ cbh,
    float* __restrict__ scf, double* lacc)
{
  const int tid = threadIdx.x;
  const int row = blockIdx.x * 4 + (tid >> 6);
  const int d = tid & 63;
  float v0 = cb[row * 128 + d];
  float v1 = cb[row * 128 + 64 + d];
  cbh[row * 128 + d]      = bf_rne(v0);
  cbh[row * 128 + 64 + d] = bf_rne(v1);
  float q0 = v0 * v0, q1 = v1 * v1;              // f32 squares (numpy chain)
  double s = (double)q0 + (double)q1;
#pragma unroll
  for (int msk = 1; msk <= 32; msk <<= 1) s += __shfl_xor(s, msk);
  if (d == 0) scf[row] = (float)s;
  if (blockIdx.x == 0 && tid == 0) *lacc = 0.0;
}

// ---- one half of the j-range: 8 windows of 16 cols, acc-resident ----
template <int JT0>
__device__ __forceinline__ void half_pass(
    const unsigned short* __restrict__ pb, const short8 (&Ah)[2][4],
    const float (&szr)[2][4], const float* __restrict__ scfl,
    int w, int lj, int lg, int R0, float* __restrict__ out,
    float (&m1)[8], float (&m2)[8], int (&i1)[8])
{
  f32x4 acc[2][8];
#pragma unroll
  for (int u = 0; u < 8; ++u) {
    acc[0][u] = (f32x4){0.f, 0.f, 0.f, 0.f};
    acc[1][u] = (f32x4){0.f, 0.f, 0.f, 0.f};
#pragma unroll
    for (int ks = 0; ks < 4; ++ks) {
      short8 bh = *reinterpret_cast<const short8*>(pb + (size_t)(JT0 + u) * 2048 + ks * 32);
      acc[0][u] = __builtin_amdgcn_mfma_f32_16x16x32_bf16(Ah[0][ks], bh, acc[0][u], 0, 0, 0);
      acc[1][u] = __builtin_amdgcn_mfma_f32_16x16x32_bf16(Ah[1][ks], bh, acc[1][u], 0, 0, 0);
    }
  }
  float sc[8];
#pragma unroll
  for (int u = 0; u < 8; ++u) sc[u] = scfl[w * 256 + (JT0 + u) * 16 + lj];
#pragma unroll
  for (int tt = 0; tt < 2; ++tt)
#pragma unroll
    for (int r = 0; r < 4; ++r) {
      const int s = tt * 4 + r;
      const float sz = szr[tt][r];
      const int row = R0 + tt * 16 + lg * 4 + r;
      float* orow = out + OFF_DIST + (size_t)row * 1024 + w * 256 + JT0 * 16 + lj;
#pragma unroll
      for (int u = 0; u < 8; ++u) {             // j ascending; adjacent 64B stores
        float dv = (sz - 2.0f * acc[tt][u][r]) + sc[u];
        bool lt1 = dv < m1[s];
        float o1 = m1[s];
        m2[s] = lt1 ? o1 : fminf(m2[s], dv);
        m1[s] = lt1 ? dv : o1;
        i1[s] = lt1 ? (w * 256 + (JT0 + u) * 16 + lj) : i1[s];
        orow[u * 16] = dv;
      }
    }
}

// ---- main: bf16 MFMA dist + prelim argmin + ambiguity flags ----
__global__ __launch_bounds__(256, 2) void vq_main(
    const float* __restrict__ z, const unsigned short* __restrict__ cbh,
    const float* __restrict__ scf, float* __restrict__ szf,
    unsigned int* __restrict__ flags, float* __restrict__ out)
{
  __shared__ __align__(16) unsigned short zh[32 * 136];
  __shared__ double part[32][8];
  __shared__ float szl[32];
  __shared__ float scfl[1024];
  __shared__ float rm1[4][32], rm2[4][32];
  __shared__ int   ri1[4][32];

  const int tid = threadIdx.x;
  const int R0 = blockIdx.x * 32;
  const int b  = R0 >> 12;
  const int t0 = R0 & 4095;
  const float* zb = z + (size_t)b * 524288;

#pragma unroll
  for (int k = 0; k < 4; ++k) scfl[k * 256 + tid] = scf[k * 256 + tid];

  {                                              // z -> bf16 LDS + ||z||^2 partials
    double ps = 0.0;
    int t = tid & 31;
#pragma unroll
    for (int k = 0; k < 16; ++k) {
      int d = k * 8 + (tid >> 5);
      float v = zb[(size_t)d * 4096 + t0 + t];
      float q = v * v; ps += (double)q;
      zh[t * 136 + d] = bf_rne(v);
    }
    part[t][tid >> 5] = ps;
  }
  __syncthreads();
  if (tid < 32) {
    double s = 0.0;
#pragma unroll
    for (int g = 0; g < 8; ++g) s += part[tid][g];
    float sz = (float)s;
    szl[tid] = sz;
    szf[R0 + tid] = sz;
  }
  __syncthreads();

  const int w = tid >> 6, l = tid & 63, lj = l & 15, lg = l >> 4;

  short8 Ah[2][4];
#pragma unroll
  for (int tt = 0; tt < 2; ++tt)
#pragma unroll
    for (int ks = 0; ks < 4; ++ks)
      Ah[tt][ks] = *reinterpret_cast<const short8*>(
          &zh[(tt * 16 + lj) * 136 + ks * 32 + lg * 8]);
  float szr[2][4];
#pragma unroll
  for (int tt = 0; tt < 2; ++tt)
#pragma unroll
    for (int r = 0; r < 4; ++r) szr[tt][r] = szl[tt * 16 + lg * 4 + r];

  const unsigned short* pb = cbh + (size_t)(w * 256 + lj) * 128 + lg * 8;

  float m1[8], m2[8]; int i1[8];
#pragma unroll
  for (int s = 0; s < 8; ++s) { m1[s] = 3.4e38f; m2[s] = 3.4e38f; i1[s] = 0; }

  half_pass<0>(pb, Ah, szr, scfl, w, lj, lg, R0, out, m1, m2, i1);
  half_pass<8>(pb, Ah, szr, scfl, w, lj, lg, R0, out, m1, m2, i1);

  // in-wave 16-lane lexicographic (val,idx) reduce, tracking min2
#pragma unroll
  for (int s = 0; s < 8; ++s) {
    float a1 = m1[s]; int ai = i1[s]; float a2 = m2[s];
#pragma unroll
    for (int msk = 1; msk <= 8; msk <<= 1) {
      float b1 = __shfl_xor(a1, msk);
      int   bi = __shfl_xor(ai, msk);
      float b2 = __shfl_xor(a2, msk);
      bool keep = (a1 < b1) || (a1 == b1 && ai < bi);
      float lose = keep ? b1 : a1;
      a2 = fminf(fminf(a2, b2), lose);
      ai = keep ? ai : bi;
      a1 = keep ? a1 : b1;
    }
    if (lj == 0) {
      int t = (s >> 2) * 16 + lg * 4 + (s & 3);
      rm1[w][t] = a1; ri1[w][t] = ai; rm2[w][t] = a2;
    }
  }
  __syncthreads();
  if (tid < 32) {
    float f1 = rm1[0][tid]; int fi = ri1[0][tid]; float f2 = rm2[0][tid];
#pragma unroll
    for (int ww = 1; ww < 4; ++ww) {
      float b1 = rm1[ww][tid]; int bi = ri1[ww][tid]; float b2 = rm2[ww][tid];
      bool keep = (f1 < b1) || (f1 == b1 && fi < bi);
      float lose = keep ? b1 : f1;
      f2 = fminf(fminf(f2, b2), lose);
      fi = keep ? fi : bi;
      f1 = keep ? f1 : b1;
    }
    int R = R0 + tid;
    out[OFF_CODES + R] = (float)fi;
    flags[R] = (f2 - f1 <= EPS) ? 1u : 0u;
  }
}

// ---- refine: flagged rows -> exact f64 dot + exact f32 chain, lex argmin ----
__global__ __launch_bounds__(256) void vq_refine(
    const float* __restrict__ z, const float* __restrict__ cb,
    const float* __restrict__ scf, const float* __restrict__ szf,
    const unsigned int* __restrict__ flags, float* __restrict__ out)
{
  const int w = threadIdx.x >> 6, l = threadIdx.x & 63;
  const int R = blockIdx.x * 4 + w;
  if (!flags[R]) return;
  const int b = R >> 12, t = R & 4095;

  const float* drow = out + OFF_DIST + (size_t)R * 1024;
  float v[16];
#pragma unroll
  for (int k = 0; k < 16; ++k) v[k] = drow[k * 64 + l];
  float mn = 3.4e38f;
#pragma unroll
  for (int k = 0; k < 16; ++k) mn = fminf(mn, v[k]);
#pragma unroll
  for (int msk = 1; msk <= 32; msk <<= 1) mn = fminf(mn, __shfl_xor(mn, msk));
  const float thresh = mn + EPS;

  const double zd0 = (double)z[(size_t)b * 524288 + (size_t)l * 4096 + t];
  const double zd1 = (double)z[(size_t)b * 524288 + (size_t)(l + 64) * 4096 + t];
  const float szv = szf[R];

  float bestv = 3.4e38f; int bestj = 1 << 30;
#pragma unroll
  for (int k = 0; k < 16; ++k) {
    unsigned long long msk = __ballot(v[k] <= thresh);
    while (msk) {
      int s = __ffsll((unsigned long long)msk) - 1;
      msk &= msk - 1;
      int jc = k * 64 + s;
      float c0 = cb[(size_t)jc * 128 + l];
      float c1 = cb[(size_t)jc * 128 + 64 + l];
      double m = zd0 * (double)c0 + zd1 * (double)c1;
#pragma unroll
      for (int mm = 1; mm <= 32; mm <<= 1) m += __shfl_xor(m, mm);
      float m32 = (float)m;
      float dvex = (szv - 2.0f * m32) + scf[jc];
      if (dvex < bestv || (dvex == bestv && jc < bestj)) { bestv = dvex; bestj = jc; }
    }
  }
  if (l == 0) out[OFF_CODES + R] = (float)bestj;
}

// ---- z_q + loss ----
__global__ __launch_bounds__(256) void vq_out_kernel(
    const float* __restrict__ z, const float* __restrict__ cb,
    float* __restrict__ out, double* __restrict__ lacc)
{
  __shared__ int ci[128];
  __shared__ float cq[128][129];
  __shared__ double lw[4];
  const int tid = threadIdx.x;
  const int b  = blockIdx.x >> 5;
  const int t0 = (blockIdx.x & 31) * 128;
  const int R0 = b * 4096 + t0;
  if (tid < 128) ci[tid] = (int)out[OFF_CODES + R0 + tid];
  __syncthreads();
  for (int r = 0; r < 128; r += 2) {
    int row = r + (tid >> 7);
    int d = tid & 127;
    cq[row][d] = cb[(size_t)ci[row] * 128 + d];
  }
  __syncthreads();
  double ls = 0.0;
  for (int dp = 0; dp < 128; dp += 2) {
    int d = dp + (tid >> 7);
    int t = tid & 127;
    size_t o = (size_t)b * 524288 + (size_t)d * 4096 + t0 + t;
    float zv = z[o];
    float q = cq[t][d];
    out[o] = zv + (q - zv);                      // straight-through f32 chain
    double dd = (double)q - (double)zv;
    ls += dd * dd;
  }
#pragma unroll
  for (int msk = 1; msk <= 32; msk <<= 1) ls += __shfl_xor(ls, msk);
  if ((tid & 63) == 0) lw[tid >> 6] = ls;
  __syncthreads();
  if (tid == 0) atomicAdd(lacc, lw[0] + lw[1] + lw[2] + lw[3]);
}

__global__ void vq_fin(const double* lacc, float* out) {
  if (threadIdx.x == 0 && blockIdx.x == 0)
    out[OFF_LOSS] = (float)(*lacc * (1.25 / 4194304.0));
}

extern "C" void kernel_launch(void* const* d_in, const int* in_sizes, int n_in,
                              void* d_out, int out_size, void* d_ws, size_t ws_size,
                              hipStream_t stream) {
  const float* z  = (const float*)d_in[0];
  const float* cb = (const float*)d_in[1];
  float* out = (float*)d_out;
  char* ws = (char*)d_ws;
  double* lacc = (double*)(ws + WS_LACC);
  float* scf = (float*)(ws + WS_SCF);
  float* szf = (float*)(ws + WS_SZF);
  unsigned int* flags = (unsigned int*)(ws + WS_FLAG);
  unsigned short* cbh = (unsigned short*)(ws + WS_CBH);

  vq_prep<<<256, 256, 0, stream>>>(cb, cbh, scf, lacc);
  vq_main<<<1024, 256, 0, stream>>>(z, cbh, scf, szf, flags, out);
  vq_refine<<<8192, 256, 0, stream>>>(z, cb, scf, szf, flags, out);
  vq_out_kernel<<<256, 256, 0, stream>>>(z, cb, out, lacc);
  vq_fin<<<1, 64, 0, stream>>>(lacc, out);
}